// Round 1
// 125.899 us; speedup vs baseline: 1.0098x; 1.0098x over previous
//
#include <hip/hip_runtime.h>
#include <math.h>

#define WIN 11
#define IMG_H 384
#define IMG_W 512
#define OUT_H (IMG_H - WIN + 1)   // 374
#define OUT_W (IMG_W - WIN + 1)   // 502
#define RPW 2                     // output rows per wave
#define NPAIRS 187                // row-pairs per image (374 = 2*187)
#define NIMG 48
#define WPB 4                     // waves per block
#define ROWS_PB (RPW * WPB)       // 8 output rows per block
#define PB_PER_IMG 47             // ceil(187/4) pair-blocks per image
#define NBLOCKS (NIMG * PB_PER_IMG)   // 2256 = 8 * 282
#define BPX 282                   // blocks per XCD
#define STAGE_ROWS (ROWS_PB + WIN - 1) // 18 input rows staged per block
#define ROW_BYTES (IMG_W * 4)     // 2048
#define SLOT_BYTES (2 * ROW_BYTES)    // X+Y per row slot = 4096
#define LDS_BYTES (STAGE_ROWS * SLOT_BYTES)  // 73728 (2 blocks/CU = 147KB <= 160KB)
#define NBUCKETS 256

typedef float v2 __attribute__((ext_vector_type(2)));

struct GaussW { float g[WIN]; };

// Fire-and-forget global->LDS DMA, 16B per lane. LDS dest is wave-uniform
// base + 16*lane (HW rule); global src is per-lane.
__device__ __forceinline__ void gload16(const void* g, void* l) {
    __builtin_amdgcn_global_load_lds(
        (const __attribute__((address_space(1))) unsigned int*)g,
        (__attribute__((address_space(3))) unsigned int*)l,
        16, 0, 0);
}

__device__ __forceinline__ v2 shfl_v2(v2 v, int src) {
    v2 r; r.x = __shfl(v.x, src, 64); r.y = __shfl(v.y, src, 64); return r;
}

__device__ __forceinline__ void horiz11_v2(const v2 (&A)[8], v2 (&out)[8],
                                           int lane, const GaussW& gw)
{
    v2 V[18];
    #pragma unroll
    for (int j = 0; j < 8; ++j) V[j] = A[j];
    #pragma unroll
    for (int j = 0; j < 8; ++j) V[8 + j] = shfl_v2(A[j], lane + 1);
    V[16] = shfl_v2(A[0], lane + 2);
    V[17] = shfl_v2(A[1], lane + 2);
    #pragma unroll
    for (int j = 0; j < 8; ++j) {
        v2 o = 0.f;
        #pragma unroll
        for (int k = 0; k < WIN; ++k) {
            v2 g = gw.g[k];
            o = __builtin_elementwise_fma(g, V[j + k], o);  // v_pk_fma_f32
        }
        out[j] = o;
    }
}

__device__ __forceinline__ void horiz11_f(const float (&A)[8], float (&out)[8],
                                          int lane, const GaussW& gw)
{
    float V[18];
    #pragma unroll
    for (int j = 0; j < 8; ++j) V[j] = A[j];
    #pragma unroll
    for (int j = 0; j < 8; ++j) V[8 + j] = __shfl(A[j], lane + 1, 64);
    V[16] = __shfl(A[0], lane + 2, 64);
    V[17] = __shfl(A[1], lane + 2, 64);
    #pragma unroll
    for (int j = 0; j < 8; ++j) {
        float o = 0.f;
        #pragma unroll
        for (int k = 0; k < WIN; ++k) o = fmaf(gw.g[k], V[j + k], o);
        out[j] = o;
    }
}

// r13 change vs r12: the 48 per-wave global_load_dwordx4 (the ~50% vmcnt
// stall at 2 waves/SIMD residency) are replaced by one block-cooperative
// global_load_lds staging pass (72 fire-and-forget 16B DMAs, ONE
// vmcnt(0)+barrier), then the vertical pass reads LDS via ds_read_b128
// with immediate offsets. Per-lane source addresses are pre-permuted
// (even 16B chunks -> [0,1024), odd -> [1024,2048) of each row) so both
// compute reads are the sequential 16*lane conflict-free pattern while
// column ownership / horizontal code stay identical to r12. Halo sharing:
// 18 staged rows serve 8 output rows (global traffic 441 -> 166 MB).
__global__ __launch_bounds__(256) void ssim_fused_kernel(
    const float* __restrict__ X, const float* __restrict__ Y,
    double* __restrict__ accum, GaussW gw)
{
    extern __shared__ char smem[];
    const int wave = threadIdx.x >> 6;
    const int lane = threadIdx.x & 63;

    const int id = blockIdx.x;
    const int wb = (id & 7) * BPX + (id >> 3);   // XCD swizzle (bijective)
    const int img = wb / PB_PER_IMG;
    const int pb  = wb - img * PB_PER_IMG;
    const int r0  = pb * ROWS_PB;

    // ---- stage: 18 rows x {X,Y} -> LDS, even/odd 16B-chunk split ----
    {
        const int t = wave >> 1, e = wave & 1;   // wave -> (tensor, parity)
        const float* tb = t ? Y : X;
        const char* src = (const char*)(tb + (size_t)img * IMG_H * IMG_W)
                          + lane * 32 + e * 16;  // chunk c = 2*lane + e
        char* dst = smem + t * ROW_BYTES + e * 1024;
        #pragma unroll
        for (int r = 0; r < STAGE_ROWS; ++r) {
            int row = r0 + r;
            row = row < IMG_H ? row : (IMG_H - 1);   // tail clamp (unused slots)
            gload16(src + (size_t)row * ROW_BYTES, dst + r * SLOT_BYTES);
        }
    }
    asm volatile("s_waitcnt vmcnt(0)" ::: "memory");
    __syncthreads();   // all staging visible; no barriers after this

    const int pair = pb * WPB + wave;            // pair within image
    if (pair < NPAIRS) {
        const int c0 = lane << 3;                // this lane's 8 columns
        // wave w's row k lives in slot 2w+k; X at +{0,1024}, Y at +{2048,3072}
        const char* lb = smem + (2 * wave) * SLOT_BYTES + lane * 16;

        // Accumulators: a01 = {m1,m2}, a23 = {xx,yy}, a4 = xy
        v2 a01[RPW][8], a23[RPW][8];
        float a4[RPW][8];
        #pragma unroll
        for (int r = 0; r < RPW; ++r)
            #pragma unroll
            for (int j = 0; j < 8; ++j) { a01[r][j] = 0.f; a23[r][j] = 0.f; a4[r][j] = 0.f; }

        #pragma unroll
        for (int k = 0; k < RPW + WIN - 1; ++k) {   // 12 input rows, all LDS
            const char* lr = lb + k * SLOT_BYTES;
            float4 xa = *(const float4*)(lr);
            float4 xb = *(const float4*)(lr + 1024);
            float4 ya = *(const float4*)(lr + ROW_BYTES);
            float4 yb = *(const float4*)(lr + ROW_BYTES + 1024);
            v2 p[8] = {{xa.x, ya.x}, {xa.y, ya.y}, {xa.z, ya.z}, {xa.w, ya.w},
                       {xb.x, yb.x}, {xb.y, yb.y}, {xb.z, yb.z}, {xb.w, yb.w}};
            #pragma unroll
            for (int r = 0; r < RPW; ++r) {
                if (k - r >= 0 && k - r < WIN) {     // compile-time after unroll
                    v2 g = gw.g[k - r];
                    #pragma unroll
                    for (int j = 0; j < 8; ++j) {
                        v2 q = p[j];
                        a01[r][j] = __builtin_elementwise_fma(g, q, a01[r][j]);
                        v2 t = g * q;                                  // {gx, gy}
                        a23[r][j] = __builtin_elementwise_fma(t, q, a23[r][j]);
                        a4[r][j]  = fmaf(t.x, q.y, a4[r][j]);          // g*x*y
                    }
                }
            }
        }

        // ---- horizontal + epilogue per row ----
        const float C1 = 1e-4f, C2 = 9e-4f;
        float sum = 0.f;
        #pragma unroll
        for (int r = 0; r < RPW; ++r) {
            v2 h01[8], h23[8];
            float h4[8];
            horiz11_v2(a01[r], h01, lane, gw);
            horiz11_v2(a23[r], h23, lane, gw);
            horiz11_f (a4[r],  h4,  lane, gw);
            #pragma unroll
            for (int j = 0; j < 8; ++j) {
                v2 mu = h01[j];
                v2 sq = mu * mu;                    // {mu1², mu2²}
                float m12 = mu.x * mu.y;
                v2 sig = h23[j] - sq;               // {s1, s2}
                float s12 = h4[j] - m12;
                float num = fmaf(2.f, m12, C1) * fmaf(2.f, s12, C2);
                float den = (sq.x + sq.y + C1) * (sig.x + sig.y + C2);
                float ssim = num * __builtin_amdgcn_rcpf(den);
                sum += (c0 + j < OUT_W) ? ssim : 0.f;
            }
        }

        // ---- wave reduction -> one f64 atomic per wave, bucketed ----
        #pragma unroll
        for (int off = 32; off; off >>= 1)
            sum += __shfl_down(sum, off, 64);
        if (lane == 0) {
            const int P = img * NPAIRS + pair;
            atomicAdd(&accum[P & (NBUCKETS - 1)], (double)sum);
        }
    }
}

__global__ void ssim_finalize_kernel(const double* __restrict__ accum,
                                     float* __restrict__ out, double inv_count)
{
    const int lane = threadIdx.x;
    double s = 0.0;
    for (int i = lane; i < NBUCKETS; i += 64) s += accum[i];
    #pragma unroll
    for (int off = 32; off; off >>= 1)
        s += __shfl_down(s, off, 64);
    if (lane == 0) out[0] = (float)(1.0 - s * inv_count);
}

extern "C" void kernel_launch(void* const* d_in, const int* in_sizes, int n_in,
                              void* d_out, int out_size, void* d_ws, size_t ws_size,
                              hipStream_t stream) {
    const float* X = (const float*)d_in[0];
    const float* Y = (const float*)d_in[1];
    float* out = (float*)d_out;
    double* accum = (double*)d_ws;

    GaussW gw;
    {
        double g[WIN], ssum = 0.0;
        for (int i = 0; i < WIN; ++i) {
            double d = (double)i - WIN / 2;
            g[i] = exp(-(d * d) / (2.0 * 1.5 * 1.5));
            ssum += g[i];
        }
        for (int i = 0; i < WIN; ++i) gw.g[i] = (float)(g[i] / ssum);
    }

    // Allow >64KB dynamic LDS (once; host-side call, not captured).
    static bool s_attr_done = false;
    if (!s_attr_done) {
        (void)hipFuncSetAttribute((const void*)ssim_fused_kernel,
                                  hipFuncAttributeMaxDynamicSharedMemorySize,
                                  LDS_BYTES);
        s_attr_done = true;
    }

    // d_ws is re-poisoned 0xAA before every call — zero the buckets.
    hipMemsetAsync(accum, 0, NBUCKETS * sizeof(double), stream);

    ssim_fused_kernel<<<NBLOCKS, 64 * WPB, LDS_BYTES, stream>>>(X, Y, accum, gw);

    const double inv_count = 1.0 / ((double)NIMG * OUT_H * OUT_W);
    ssim_finalize_kernel<<<1, 64, 0, stream>>>(accum, out, inv_count);
}